// Round 7
// baseline (86.322 us; speedup 1.0000x reference)
//
#include <hip/hip_runtime.h>

// Problem constants (x: [128, 65536] fp32, LEVEL=8)
static constexpr int BROWS = 128;   // batch rows
static constexpr int T     = 65536; // samples per row
static constexpr int CL    = 256;   // chunk length = 2^LEVEL
static constexpr int NCH   = 256;   // chunks per row = T / CL (positions per node)
static constexpr int NODES = 256;   // 2^LEVEL leaves
static constexpr int KG    = 32;    // chunks handled per block in wht_kernel
static constexpr int LSTR  = 257;   // padded LDS row stride (breaks bank conflicts)

// Output row for Hadamard-order index h (slot-bit bookkeeping is stage-order
// independent): c_nat[n] = H[bitrev8(n)], freq perm => m = gray(bitrev8(h))
__device__ __forceinline__ int freq_pos(int h) {
    unsigned r = __brev((unsigned)h) >> 24; // bitrev8
    return (int)(r ^ (r >> 1));             // gray code
}

// Register-pair butterfly: (u,v) -> (u+v, u-v)
__device__ __forceinline__ void bflyreg(float4& u, float4& v) {
    float4 t;
    t.x = u.x - v.x; t.y = u.y - v.y; t.z = u.z - v.z; t.w = u.w - v.w;
    u.x += v.x; u.y += v.y; u.z += v.z; u.w += v.w;
    v = t;
}

__device__ __forceinline__ void bfly01(float4& v) {
    // FWHT stages on j-bits 0,1 (within the float4)
    float4 w;
    w.x = v.x + v.y; w.y = v.x - v.y;
    w.z = v.z + v.w; w.w = v.z - v.w;
    v.x = w.x + w.z; v.z = w.x - w.z;
    v.y = w.y + w.w; v.w = w.y - w.w;
}

// Lane-exchange via DPP (VALU pipe — no LDS traffic). HW-validated R4/R5.
// xor1 = quad_perm [1,0,3,2] = 0xB1; xor2 = quad_perm [2,3,0,1] = 0x4E;
// xor8 = row_ror:8 = 0x128 ((i+8)%16 == i^8 within a 16-lane row).
template<int CTRL>
__device__ __forceinline__ float xchg_dpp(float v) {
    return __builtin_bit_cast(float,
        __builtin_amdgcn_update_dpp(0, __builtin_bit_cast(int, v), CTRL, 0xF, 0xF, true));
}

template<int CTRL>
__device__ __forceinline__ void stage_dpp1(float4& v, float sgn) {
    float o;
    o = xchg_dpp<CTRL>(v.x); v.x = fmaf(sgn, v.x, o);
    o = xchg_dpp<CTRL>(v.y); v.y = fmaf(sgn, v.y, o);
    o = xchg_dpp<CTRL>(v.z); v.z = fmaf(sgn, v.z, o);
    o = xchg_dpp<CTRL>(v.w); v.w = fmaf(sgn, v.w, o);
}

__device__ __forceinline__ void stage_shfl1(float4& v, float sgn, int mask) {
    float o;
    o = __shfl_xor(v.x, mask, 64); v.x = fmaf(sgn, v.x, o);
    o = __shfl_xor(v.y, mask, 64); v.y = fmaf(sgn, v.y, o);
    o = __shfl_xor(v.z, mask, 64); v.z = fmaf(sgn, v.z, o);
    o = __shfl_xor(v.w, mask, 64); v.w = fmaf(sgn, v.w, o);
}

// Per block: 32 chunks of one batch row -> 256-pt FWHT.
// Layout: each lane holds 16 elements (4 float4s) of ONE chunk:
//   j = i + 4*p0 + 8*p1 + 16*q0 + 32*p2 + 64*p3 + 128*q1
// where i = float4 elem (j-bits 0,1), p = lane&15 (j-bits 2,3,5,6),
// q = register index (j-bits 4,7), chunk = lane>>4 (4 chunks per wave-iter).
// Register bits absorb the mask-16 butterfly -> only mask 4 uses the LDS pipe.
__global__ __launch_bounds__(256) void wht_kernel(const float* __restrict__ x,
                                                  float* __restrict__ coeffs,
                                                  float* __restrict__ part) {
    __shared__ float lds[KG][LSTR]; // 32.9 KB

    const int b    = blockIdx.x >> 3;  // 8 chunk-groups per row
    const int kg   = blockIdx.x & 7;
    const int k0   = kg * KG;
    const int tid  = threadIdx.x;
    const int lane = tid & 63;
    const int wave = tid >> 6;         // 4 waves
    const int p    = lane & 15;        // position bits (j-bits 2,3,5,6)
    const int cg   = lane >> 4;        // chunk-group 0..3 within wave

    const float* xb = x + (size_t)b * T;

    const int p0 = p & 1, p1 = (p >> 1) & 1, p2 = (p >> 2) & 1, p3 = (p >> 3) & 1;
    const int offs = 4 * p0 + 8 * p1 + 32 * p2 + 64 * p3;

    // freq positions for the 16 nodes this lane owns (same for every chunk)
    int npos[4][4];
    #pragma unroll
    for (int q = 0; q < 4; ++q)
        #pragma unroll
        for (int i = 0; i < 4; ++i)
            npos[q][i] = freq_pos(i + offs + 16 * (q & 1) + 128 * (q >> 1));

    // Butterfly signs for the cross-lane stages
    const float sA = 1.0f - 2.0f * (float)p0; // j-bit2, mask 1
    const float sB = 1.0f - 2.0f * (float)p1; // j-bit3, mask 2
    const float sC = 1.0f - 2.0f * (float)p2; // j-bit5, mask 4
    const float sD = 1.0f - 2.0f * (float)p3; // j-bit6, mask 8

    // 2 iterations x 4 chunks per wave = 8 chunks; block covers 32
    #pragma unroll
    for (int it = 0; it < 2; ++it) {
        const int kl = wave * 8 + it * 4 + cg; // local chunk row in LDS
        const float* cp = xb + (size_t)(k0 + kl) * CL + offs;
        float4 V0 = *(const float4*)(cp);        // q0=0 q1=0
        float4 V1 = *(const float4*)(cp + 16);   // q0=1 q1=0
        float4 V2 = *(const float4*)(cp + 128);  // q0=0 q1=1
        float4 V3 = *(const float4*)(cp + 144);  // q0=1 q1=1

        // j-bit7 (register bit q1) and j-bit4 (register bit q0): pure VALU
        bflyreg(V0, V2); bflyreg(V1, V3);
        bflyreg(V0, V1); bflyreg(V2, V3);
        // j-bits 0,1 intra-float4
        bfly01(V0); bfly01(V1); bfly01(V2); bfly01(V3);
        // lane stages: masks 1,2,8 on VALU (DPP); mask 4 on LDS pipe
        stage_dpp1<0xB1>(V0, sA); stage_dpp1<0xB1>(V1, sA);
        stage_dpp1<0xB1>(V2, sA); stage_dpp1<0xB1>(V3, sA);
        stage_dpp1<0x4E>(V0, sB); stage_dpp1<0x4E>(V1, sB);
        stage_dpp1<0x4E>(V2, sB); stage_dpp1<0x4E>(V3, sB);
        stage_shfl1(V0, sC, 4);   stage_shfl1(V1, sC, 4);
        stage_shfl1(V2, sC, 4);   stage_shfl1(V3, sC, 4);
        stage_dpp1<0x128>(V0, sD); stage_dpp1<0x128>(V1, sD);
        stage_dpp1<0x128>(V2, sD); stage_dpp1<0x128>(V3, sD);

        // scale by (1/sqrt2)^8 = 1/16; scatter to freq-ordered LDS row
        float* row = lds[kl];
        row[npos[0][0]] = V0.x * 0.0625f; row[npos[0][1]] = V0.y * 0.0625f;
        row[npos[0][2]] = V0.z * 0.0625f; row[npos[0][3]] = V0.w * 0.0625f;
        row[npos[1][0]] = V1.x * 0.0625f; row[npos[1][1]] = V1.y * 0.0625f;
        row[npos[1][2]] = V1.z * 0.0625f; row[npos[1][3]] = V1.w * 0.0625f;
        row[npos[2][0]] = V2.x * 0.0625f; row[npos[2][1]] = V2.y * 0.0625f;
        row[npos[2][2]] = V2.z * 0.0625f; row[npos[2][3]] = V2.w * 0.0625f;
        row[npos[3][0]] = V3.x * 0.0625f; row[npos[3][1]] = V3.y * 0.0625f;
        row[npos[3][2]] = V3.z * 0.0625f; row[npos[3][3]] = V3.w * 0.0625f;
    }
    __syncthreads();

    // Transposed, coalesced write + fused entropy partials.
    // Thread (kk = (tid&7)*4, m0 = tid>>3) handles nodes m = pw*32+m0,
    // k-slice [k0+kk, k0+kk+4). The 8 threads sharing m (kk = 0..28) reduce
    // A = sum c^2 and B = sum c^2 log c^2 via DPP/shfl, lane-bits 0..2.
    float* ob = coeffs + (size_t)b * T + k0;
    float* pp = part + (size_t)blockIdx.x * 512;
    const int kk = (tid & 7) * 4;
    const int m0 = tid >> 3;
    #pragma unroll
    for (int pw = 0; pw < 8; ++pw) {
        const int m = pw * 32 + m0;
        float4 v;
        v.x = lds[kk + 0][m];
        v.y = lds[kk + 1][m];
        v.z = lds[kk + 2][m];
        v.w = lds[kk + 3][m];
        *(float4*)(ob + (size_t)m * NCH + kk) = v;

        const float qx = v.x * v.x, qy = v.y * v.y, qz = v.z * v.z, qw = v.w * v.w;
        float A = qx + qy + qz + qw;
        float B = qx * __logf(qx + 1e-35f) + qy * __logf(qy + 1e-35f)
                + qz * __logf(qz + 1e-35f) + qw * __logf(qw + 1e-35f);
        A += xchg_dpp<0xB1>(A);  B += xchg_dpp<0xB1>(B);   // xor 1
        A += xchg_dpp<0x4E>(A);  B += xchg_dpp<0x4E>(B);   // xor 2
        A += __shfl_xor(A, 4, 64); B += __shfl_xor(B, 4, 64); // xor 4
        if ((tid & 7) == 0) {
            pp[m]       = A;
            pp[256 + m] = B;
        }
    }
}

// One thread per (b, n): sum the 8 block-partials, entropy = (A*logS - B)/S,
// S = A + 1e-8. Zero the coeff row only when !keep (rare for Gaussian input).
__global__ __launch_bounds__(256) void finalize_kernel(const float* __restrict__ part,
                                                       float* __restrict__ coeffs,
                                                       float* __restrict__ entropy,
                                                       float* __restrict__ keep) {
    const int row = blockIdx.x * 256 + threadIdx.x; // b*256 + n
    const int b = row >> 8;
    const int n = row & 255;

    float A = 0.f, B = 0.f;
    #pragma unroll
    for (int g = 0; g < 8; ++g) {
        const float* p = part + (size_t)(b * 8 + g) * 512;
        A += p[n];
        B += p[256 + n];
    }

    const float S = A + 1e-8f;
    const float e = (A * __logf(S) - B) / S;
    const bool kp = e > 0.1f;

    entropy[row] = e;
    keep[row]    = kp ? 1.0f : 0.0f;

    if (!kp) {
        float4 z = make_float4(0.f, 0.f, 0.f, 0.f);
        float4* cp = (float4*)(coeffs + (size_t)row * NCH);
        #pragma unroll
        for (int j = 0; j < NCH / 4; ++j) cp[j] = z;
    }
}

extern "C" void kernel_launch(void* const* d_in, const int* in_sizes, int n_in,
                              void* d_out, int out_size, void* d_ws, size_t ws_size,
                              hipStream_t stream) {
    const float* x = (const float*)d_in[0];

    float* coeffs  = (float*)d_out;                         // [128][256][256]
    float* entropy = coeffs + (size_t)BROWS * NODES * NCH;  // [128][256]
    float* keepf   = entropy + (size_t)BROWS * NODES;       // [128][256] as 0/1 float

    float* part = (float*)d_ws; // [1024 blocks][2][256] = 2 MB

    wht_kernel<<<dim3(BROWS * (NCH / KG)), dim3(256), 0, stream>>>(x, coeffs, part);
    finalize_kernel<<<dim3(BROWS * NODES / 256), dim3(256), 0, stream>>>(part, coeffs, entropy, keepf);
}

// Round 8
// 84.840 us; speedup vs baseline: 1.0175x; 1.0175x over previous
//
#include <hip/hip_runtime.h>

// Problem constants (x: [128, 65536] fp32, LEVEL=8)
static constexpr int BROWS = 128;   // batch rows
static constexpr int T     = 65536; // samples per row
static constexpr int CL    = 256;   // chunk length = 2^LEVEL
static constexpr int NCH   = 256;   // chunks per row = T / CL (positions per node)
static constexpr int NODES = 256;   // 2^LEVEL leaves
static constexpr int KG    = 32;    // chunks handled per block in wht_kernel
static constexpr int LSTR  = 257;   // padded LDS row stride (breaks bank conflicts)

// Output row for Hadamard-order index h (in-place FWHT leaves Hadamard order):
//   c_nat[n] = H[bitrev8(n)], freq perm out[m] = c_nat[gray^-1(m)] => m = gray(bitrev8(h))
__device__ __forceinline__ int freq_pos(int h) {
    unsigned r = __brev((unsigned)h) >> 24; // bitrev8
    return (int)(r ^ (r >> 1));             // gray code
}

__device__ __forceinline__ void bfly01(float4& v) {
    // FWHT stages on j-bits 0,1 (within the float4)
    float4 w;
    w.x = v.x + v.y; w.y = v.x - v.y;
    w.z = v.z + v.w; w.w = v.z - v.w;
    v.x = w.x + w.z; v.z = w.x - w.z;
    v.y = w.y + w.w; v.w = w.y - w.w;
}

// Lane-exchange via DPP (VALU pipe — no LDS traffic). HW-validated R4/R5.
// xor1 = quad_perm [1,0,3,2] = 0xB1; xor2 = quad_perm [2,3,0,1] = 0x4E;
// xor8 = row_ror:8 = 0x128 ((i+8)%16 == i^8 within a 16-lane row).
template<int CTRL>
__device__ __forceinline__ float xchg_dpp(float v) {
    return __builtin_bit_cast(float,
        __builtin_amdgcn_update_dpp(0, __builtin_bit_cast(int, v), CTRL, 0xF, 0xF, true));
}

template<int CTRL>
__device__ __forceinline__ void stage_dpp(float4& v1, float4& v2, float sgn) {
    float o;
    o = xchg_dpp<CTRL>(v1.x); v1.x = fmaf(sgn, v1.x, o);
    o = xchg_dpp<CTRL>(v1.y); v1.y = fmaf(sgn, v1.y, o);
    o = xchg_dpp<CTRL>(v1.z); v1.z = fmaf(sgn, v1.z, o);
    o = xchg_dpp<CTRL>(v1.w); v1.w = fmaf(sgn, v1.w, o);
    o = xchg_dpp<CTRL>(v2.x); v2.x = fmaf(sgn, v2.x, o);
    o = xchg_dpp<CTRL>(v2.y); v2.y = fmaf(sgn, v2.y, o);
    o = xchg_dpp<CTRL>(v2.z); v2.z = fmaf(sgn, v2.z, o);
    o = xchg_dpp<CTRL>(v2.w); v2.w = fmaf(sgn, v2.w, o);
}

__device__ __forceinline__ void stage_shfl(float4& v1, float4& v2, float sgn, int mask) {
    float o;
    o = __shfl_xor(v1.x, mask, 64); v1.x = fmaf(sgn, v1.x, o);
    o = __shfl_xor(v1.y, mask, 64); v1.y = fmaf(sgn, v1.y, o);
    o = __shfl_xor(v1.z, mask, 64); v1.z = fmaf(sgn, v1.z, o);
    o = __shfl_xor(v1.w, mask, 64); v1.w = fmaf(sgn, v1.w, o);
    o = __shfl_xor(v2.x, mask, 64); v2.x = fmaf(sgn, v2.x, o);
    o = __shfl_xor(v2.y, mask, 64); v2.y = fmaf(sgn, v2.y, o);
    o = __shfl_xor(v2.z, mask, 64); v2.z = fmaf(sgn, v2.z, o);
    o = __shfl_xor(v2.w, mask, 64); v2.w = fmaf(sgn, v2.w, o);
}

// Per block: 32 chunks of one batch row -> 256-pt FWHT (dual-chunk wave layout)
// -> freq-ordered transposed coeffs write + per-node entropy partials into ws.
__global__ __launch_bounds__(256) void wht_kernel(const float* __restrict__ x,
                                                  float* __restrict__ coeffs,
                                                  float* __restrict__ part) {
    __shared__ float lds[KG][LSTR]; // 32.9 KB; reused as 4x2x256 partial buffer later

    const int b    = blockIdx.x >> 3;  // 8 chunk-groups per row
    const int kg   = blockIdx.x & 7;
    const int k0   = kg * KG;
    const int lane = threadIdx.x & 63;
    const int wave = threadIdx.x >> 6; // 4 waves
    const int half = lane >> 5;        // which of 2 concurrent chunks
    const int L    = lane & 31;        // position within chunk (j-bits 2..6)

    const float* xb = x + (size_t)b * T;

    // lane owns the SAME 8 nodes (h = 4L+i and 128+4L+i) in every chunk
    int npos1[4], npos2[4];
    #pragma unroll
    for (int i = 0; i < 4; ++i) {
        npos1[i] = freq_pos(4 * L + i);
        npos2[i] = freq_pos(128 + 4 * L + i);
    }
    float A1[4] = {0.f,0.f,0.f,0.f}, B1[4] = {0.f,0.f,0.f,0.f};
    float A2[4] = {0.f,0.f,0.f,0.f}, B2[4] = {0.f,0.f,0.f,0.f};

    // Butterfly signs for the 5 cross-lane stages (loop-invariant)
    const float sgn0 = 1.0f - 2.0f * (float)((L >> 0) & 1);
    const float sgn1 = 1.0f - 2.0f * (float)((L >> 1) & 1);
    const float sgn2 = 1.0f - 2.0f * (float)((L >> 2) & 1);
    const float sgn3 = 1.0f - 2.0f * (float)((L >> 3) & 1);
    const float sgn4 = 1.0f - 2.0f * (float)((L >> 4) & 1);

    // Each wave handles 8 chunks as 4 iterations x 2 chunks (one per lane-half)
    #pragma unroll
    for (int it = 0; it < 4; ++it) {
        const int kl = wave * 8 + it * 2 + half; // local chunk row in LDS
        const float* cp = xb + (size_t)(k0 + kl) * CL + 4 * L;
        float4 v1 = *(const float4*)(cp);        // j = 4L+i      (bit7=0)
        float4 v2 = *(const float4*)(cp + 128);  // j = 128+4L+i  (bit7=1)

        // FWHT stage j-bit7 (across the two registers, pure VALU)
        float4 t;
        t.x = v1.x - v2.x; t.y = v1.y - v2.y; t.z = v1.z - v2.z; t.w = v1.w - v2.w;
        v1.x += v2.x; v1.y += v2.y; v1.z += v2.z; v1.w += v2.w;
        v2 = t;

        // FWHT stages j-bits 0,1 (intra-float4)
        bfly01(v1);
        bfly01(v2);

        // FWHT stages j-bits 2..6 = lane xor 1,2,4,8,16.
        // Masks 1,2,8 run on the VALU via DPP; masks 4,16 stay on the LDS pipe.
        stage_dpp<0xB1>(v1, v2, sgn0);   // xor 1  (quad_perm [1,0,3,2])
        stage_dpp<0x4E>(v1, v2, sgn1);   // xor 2  (quad_perm [2,3,0,1])
        stage_shfl(v1, v2, sgn2, 4);     // xor 4  (ds_swizzle)
        stage_dpp<0x128>(v1, v2, sgn3);  // xor 8  (row_ror:8)
        stage_shfl(v1, v2, sgn4, 16);    // xor 16 (ds_swizzle)

        // scale by (1/sqrt2)^8 = 1/16; accumulate entropy partials; LDS scatter
        float c1[4] = {v1.x*0.0625f, v1.y*0.0625f, v1.z*0.0625f, v1.w*0.0625f};
        float c2[4] = {v2.x*0.0625f, v2.y*0.0625f, v2.z*0.0625f, v2.w*0.0625f};
        #pragma unroll
        for (int i = 0; i < 4; ++i) {
            const float s1 = c1[i] * c1[i];
            A1[i] += s1;
            B1[i] += s1 * __logf(s1 + 1e-35f); // c=0 -> term 0, matches p*log(p+eps)
            lds[kl][npos1[i]] = c1[i];
            const float s2 = c2[i] * c2[i];
            A2[i] += s2;
            B2[i] += s2 * __logf(s2 + 1e-35f);
            lds[kl][npos2[i]] = c2[i];
        }
    }
    __syncthreads();

    // Transposed, coalesced write: coeffs[b][m][k0 + kk .. kk+3]
    float* ob = coeffs + (size_t)b * T + k0;
    const int kk = (threadIdx.x & 7) * 4; // k offset within group
    const int m0 = threadIdx.x >> 3;      // 0..31
    #pragma unroll
    for (int p = 0; p < 8; ++p) {
        const int m = p * 32 + m0;
        float4 v;
        v.x = lds[kk + 0][m];
        v.y = lds[kk + 1][m];
        v.z = lds[kk + 2][m];
        v.w = lds[kk + 3][m];
        *(float4*)(ob + (size_t)m * NCH + kk) = v;
    }
    __syncthreads();

    // Merge the two lane-halves (same node sets), then cross-wave reduce via LDS
    #pragma unroll
    for (int i = 0; i < 4; ++i) {
        A1[i] += __shfl_xor(A1[i], 32, 64); B1[i] += __shfl_xor(B1[i], 32, 64);
        A2[i] += __shfl_xor(A2[i], 32, 64); B2[i] += __shfl_xor(B2[i], 32, 64);
    }
    float* pl = &lds[0][0]; // need 4*512 = 2048 floats, have 8224
    if (half == 0) {
        #pragma unroll
        for (int i = 0; i < 4; ++i) {
            pl[wave * 512 + npos1[i]]       = A1[i];
            pl[wave * 512 + 256 + npos1[i]] = B1[i];
            pl[wave * 512 + npos2[i]]       = A2[i];
            pl[wave * 512 + 256 + npos2[i]] = B2[i];
        }
    }
    __syncthreads();

    const int n = threadIdx.x; // 0..255 = node
    const float A = pl[n] + pl[512 + n] + pl[1024 + n] + pl[1536 + n];
    const float B = pl[256 + n] + pl[768 + n] + pl[1280 + n] + pl[1792 + n];
    float* pp = part + (size_t)blockIdx.x * 512;
    pp[n]       = A;
    pp[256 + n] = B;
}

// One thread per (b, n): sum the 8 block-partials, entropy = (A*logS - B)/S,
// S = A + 1e-8. Zero the coeff row only when !keep (rare for Gaussian input).
__global__ __launch_bounds__(256) void finalize_kernel(const float* __restrict__ part,
                                                       float* __restrict__ coeffs,
                                                       float* __restrict__ entropy,
                                                       float* __restrict__ keep) {
    const int row = blockIdx.x * 256 + threadIdx.x; // b*256 + n
    const int b = row >> 8;
    const int n = row & 255;

    float A = 0.f, B = 0.f;
    #pragma unroll
    for (int g = 0; g < 8; ++g) {
        const float* p = part + (size_t)(b * 8 + g) * 512;
        A += p[n];
        B += p[256 + n];
    }

    const float S = A + 1e-8f;
    const float e = (A * __logf(S) - B) / S;
    const bool kp = e > 0.1f;

    entropy[row] = e;
    keep[row]    = kp ? 1.0f : 0.0f;

    if (!kp) {
        float4 z = make_float4(0.f, 0.f, 0.f, 0.f);
        float4* cp = (float4*)(coeffs + (size_t)row * NCH);
        #pragma unroll
        for (int j = 0; j < NCH / 4; ++j) cp[j] = z;
    }
}

extern "C" void kernel_launch(void* const* d_in, const int* in_sizes, int n_in,
                              void* d_out, int out_size, void* d_ws, size_t ws_size,
                              hipStream_t stream) {
    const float* x = (const float*)d_in[0];

    float* coeffs  = (float*)d_out;                         // [128][256][256]
    float* entropy = coeffs + (size_t)BROWS * NODES * NCH;  // [128][256]
    float* keepf   = entropy + (size_t)BROWS * NODES;       // [128][256] as 0/1 float

    float* part = (float*)d_ws; // [1024 blocks][2][256] = 2 MB

    wht_kernel<<<dim3(BROWS * (NCH / KG)), dim3(256), 0, stream>>>(x, coeffs, part);
    finalize_kernel<<<dim3(BROWS * NODES / 256), dim3(256), 0, stream>>>(part, coeffs, entropy, keepf);
}